// Round 2
// baseline (1334.110 us; speedup 1.0000x reference)
//
#include <hip/hip_runtime.h>
#include <hip/hip_bf16.h>
#include <stdint.h>
#include <stddef.h>

// ---------------------------------------------------------------------------
// Swin-V2 window attention, MI355X.  fp16-hi/lo ("fp16x2") everywhere.
//   qkv GEMM (W-major, 3-phase)  ->  MFMA attention (fp16, P hi/lo via LDS)
//   -> proj GEMM (2-phase).
// GEMM0 epilogue emits q,k row-major and V TRANSPOSED, all in fp16 hi/lo,
// exactly matching the attention kernel's 16x16x32 fragment layouts.
// ---------------------------------------------------------------------------

typedef unsigned short ushort_t;
typedef _Float16 half_t;
typedef __attribute__((ext_vector_type(8))) _Float16 half8;   // 4 VGPR
typedef __attribute__((ext_vector_type(4))) float f32x4;

#define MROWS 65536   // 1024 windows * 64 tokens

__device__ __forceinline__ ushort_t h_bits(half_t h) {
  union { half_t h; ushort_t u; } c; c.h = h; return c.u;
}

// ---------------- split fp32 -> fp16 hi + fp16 lo --------------------------
__global__ __launch_bounds__(256) void k_split(const float* __restrict__ src,
                                               ushort_t* __restrict__ hi,
                                               ushort_t* __restrict__ lo, int n4) {
  int stride = gridDim.x * blockDim.x;
  for (int i = blockIdx.x * blockDim.x + threadIdx.x; i < n4; i += stride) {
    f32x4 x = reinterpret_cast<const f32x4*>(src)[i];
    ushort_t h4[4], l4[4];
#pragma unroll
    for (int j = 0; j < 4; ++j) {
      half_t hh = (half_t)x[j];
      h4[j] = h_bits(hh);
      l4[j] = h_bits((half_t)(x[j] - (float)hh));
    }
    uint2 hv = make_uint2(h4[0] | ((unsigned)h4[1] << 16), h4[2] | ((unsigned)h4[3] << 16));
    uint2 lv = make_uint2(l4[0] | ((unsigned)l4[1] << 16), l4[2] | ((unsigned)l4[3] << 16));
    reinterpret_cast<uint2*>(hi)[i] = hv;
    reinterpret_cast<uint2*>(lo)[i] = lv;
  }
}

// ---------------- CPB MLP: 225 positions -> 16*sigmoid table ---------------
__global__ __launch_bounds__(256) void k_cpb1(const float* __restrict__ coords,
                                              const float* __restrict__ w1,
                                              const float* __restrict__ b1,
                                              const float* __restrict__ w2,
                                              float* __restrict__ tbl) {
  __shared__ float hid[512];
  int p = blockIdx.x;
  float c0 = coords[2 * p], c1 = coords[2 * p + 1];
  int t = threadIdx.x;
  for (int j = t; j < 512; j += 256) {
    float v = c0 * w1[2 * j] + c1 * w1[2 * j + 1] + b1[j];
    hid[j] = v > 0.f ? v : 0.f;
  }
  __syncthreads();
  int wid = t >> 6, lane = t & 63;
#pragma unroll
  for (int hh = 0; hh < 4; ++hh) {
    int head = wid * 4 + hh;
    float s = 0.f;
    for (int j = lane; j < 512; j += 64) s += hid[j] * w2[head * 512 + j];
#pragma unroll
    for (int off = 32; off > 0; off >>= 1) s += __shfl_xor(s, off);
    if (lane == 0) tbl[p * 16 + head] = 16.f / (1.f + __expf(-s));
  }
}

__global__ __launch_bounds__(256) void k_cpb2(const float* __restrict__ tbl,
                                              const int* __restrict__ ridx,
                                              float* __restrict__ rpb) {
  int idx = blockIdx.x * 256 + threadIdx.x;   // 65536 = 16 heads * 4096
  int h = idx >> 12, nm = idx & 4095;
  rpb[idx] = tbl[ridx[nm] * 16 + h];
}

// ---------------- GEMM: C[ch, tok] = W[ch,K] * X[tok,K]^T  (fp16x2) --------
__device__ __forceinline__ void gload16(const void* g, void* l) {
  __builtin_amdgcn_global_load_lds(
      (const __attribute__((address_space(1))) unsigned int*)g,
      (__attribute__((address_space(3))) unsigned int*)l, 16, 0, 0);
}

// EPI 0: qkv epilogue -> q,k [pair][n][d] fp16 hi/lo ; v transposed [pair][d][n] hi only
// EPI 1: proj epilogue -> fp32 out[tok][512] (f32x4 stores)
template <int EPI>
__global__ __launch_bounds__(256) void k_gemm(
    const ushort_t* __restrict__ Ah, const ushort_t* __restrict__ Al,
    const ushort_t* __restrict__ Bh, const ushort_t* __restrict__ Bl,
    int ntm,
    const float* __restrict__ qb, const float* __restrict__ vb,
    ushort_t* __restrict__ oqh, ushort_t* __restrict__ oql,
    ushort_t* __restrict__ okh, ushort_t* __restrict__ okl,
    ushort_t* __restrict__ ovt,
    const float* __restrict__ pb, float* __restrict__ outp) {
  constexpr int NPH = (EPI == 0) ? 3 : 2;
  __shared__ ushort_t lA[2][128 * 32];
  __shared__ ushort_t lB[2][128 * 32];

  int nwg = gridDim.x, bid = blockIdx.x;
  int idx = ((nwg & 7) == 0) ? ((bid & 7) * (nwg >> 3) + (bid >> 3)) : bid;
  int tm = idx % ntm;          // weight tile (channels)
  int tn = idx / ntm;          // token tile
  int tid = threadIdx.x;
  int wid = tid >> 6, lane = tid & 63;
  int wr = wid >> 1, wc = wid & 1;
  int lr = lane & 15, lq = lane >> 4;

  // staging: thread-constant base pointers, per-step immediate offsets
  int rowA = tid >> 2;                         // 0..63
  int sw8 = ((tid & 3) ^ (rowA & 3)) * 8;      // source-side XOR swizzle
  const ushort_t* a0h = Ah + (size_t)(tm * 128 + rowA) * 512 + sw8;
  const ushort_t* a1h = a0h + 64 * 512;
  const ushort_t* a0l = Al + (size_t)(tm * 128 + rowA) * 512 + sw8;
  const ushort_t* a1l = a0l + 64 * 512;
  const ushort_t* b0h = Bh + (size_t)(tn * 128 + rowA) * 512 + sw8;
  const ushort_t* b1h = b0h + 64 * 512;
  const ushort_t* b0l = Bl + (size_t)(tn * 128 + rowA) * 512 + sw8;
  const ushort_t* b1l = b0l + 64 * 512;
  ushort_t* dA0[2] = {&lA[0][wid * 512], &lA[1][wid * 512]};
  ushort_t* dA1[2] = {&lA[0][2048 + wid * 512], &lA[1][2048 + wid * 512]};
  ushort_t* dB0[2] = {&lB[0][wid * 512], &lB[1][wid * 512]};
  ushort_t* dB1[2] = {&lB[0][2048 + wid * 512], &lB[1][2048 + wid * 512]};

  f32x4 acc[4][4];
#pragma unroll
  for (int i = 0; i < 4; ++i)
#pragma unroll
    for (int j = 0; j < 4; ++j)
#pragma unroll
      for (int r = 0; r < 4; ++r) acc[i][j][r] = 0.f;

  auto stage = [&](int t, int bs) {
    int kk = (t & 15) * 32;
    const ushort_t *A0, *A1, *B0, *B1;
    if constexpr (EPI == 0) {          // phases: AhBh, AhBl, AlBh
      A0 = (t < 32) ? a0h : a0l;  A1 = (t < 32) ? a1h : a1l;
      B0 = (t >= 16 && t < 32) ? b0l : b0h;
      B1 = (t >= 16 && t < 32) ? b1l : b1h;
    } else {                           // phases: AhBh, AlBh
      A0 = (t < 16) ? a0h : a0l;  A1 = (t < 16) ? a1h : a1l;
      B0 = b0h;  B1 = b1h;
    }
    gload16(A0 + kk, dA0[bs]);
    gload16(A1 + kk, dA1[bs]);
    gload16(B0 + kk, dB0[bs]);
    gload16(B1 + kk, dB1[bs]);
  };

  stage(0, 0);
  constexpr int NT = NPH * 16;
#pragma unroll
  for (int t = 0; t < NT; ++t) {
    __syncthreads();
    if (t + 1 < NT) stage(t + 1, (t + 1) & 1);
    int bs = t & 1;
    int c16 = (lq ^ (lr & 3)) * 8;     // inverse swizzle on the read side
    half8 af[4], bf[4];
#pragma unroll
    for (int i = 0; i < 4; ++i)
      af[i] = *(const half8*)&lA[bs][(wr * 64 + i * 16 + lr) * 32 + c16];
#pragma unroll
    for (int j = 0; j < 4; ++j)
      bf[j] = *(const half8*)&lB[bs][(wc * 64 + j * 16 + lr) * 32 + c16];
#pragma unroll
    for (int i = 0; i < 4; ++i)
#pragma unroll
      for (int j = 0; j < 4; ++j)
        acc[i][j] = __builtin_amdgcn_mfma_f32_16x16x32_f16(af[i], bf[j], acc[i][j], 0, 0, 0);
  }

  // C layout (verified): col = lane&15, row = (lane>>4)*4 + reg
  // W-major: row = out-channel, col = token.
#pragma unroll
  for (int i = 0; i < 4; ++i) {
    int ch0 = tm * 128 + wr * 64 + i * 16 + lq * 4;
#pragma unroll
    for (int j = 0; j < 4; ++j) {
      int tok = tn * 128 + wc * 64 + j * 16 + lr;
      if constexpr (EPI == 0) {
        int sec = tm >> 2;                 // block-uniform: 0=q,1=k,2=v
        int h = (ch0 >> 5) & 15, d0 = ch0 & 31;
        int win = tok >> 6, n = tok & 63;
        size_t pr = (size_t)win * 16 + h;
        f32x4 b4;
        if (sec == 0)      b4 = *(const f32x4*)&qb[ch0];
        else if (sec == 2) b4 = *(const f32x4*)&vb[ch0 - 1024];
        else { b4[0] = 0.f; b4[1] = 0.f; b4[2] = 0.f; b4[3] = 0.f; }
        if (sec == 2) {
#pragma unroll
          for (int r = 0; r < 4; ++r) {
            float v = acc[i][j][r] + b4[r];
            ovt[(pr * 32 + d0 + r) * 64 + n] = h_bits((half_t)v);
          }
        } else {
          ushort_t hb[4], lb[4];
#pragma unroll
          for (int r = 0; r < 4; ++r) {
            float v = acc[i][j][r] + b4[r];
            half_t hh = (half_t)v;
            hb[r] = h_bits(hh);
            lb[r] = h_bits((half_t)(v - (float)hh));
          }
          uint2 hw = make_uint2(hb[0] | ((unsigned)hb[1] << 16), hb[2] | ((unsigned)hb[3] << 16));
          uint2 lw = make_uint2(lb[0] | ((unsigned)lb[1] << 16), lb[2] | ((unsigned)lb[3] << 16));
          size_t o = (pr * 64 + n) * 32 + d0;
          if (sec == 0) { *(uint2*)&oqh[o] = hw; *(uint2*)&oql[o] = lw; }
          else          { *(uint2*)&okh[o] = hw; *(uint2*)&okl[o] = lw; }
        }
      } else {
        f32x4 b4 = *(const f32x4*)&pb[ch0];
        f32x4 o;
#pragma unroll
        for (int r = 0; r < 4; ++r) o[r] = acc[i][j][r] + b4[r];
        *(f32x4*)&outp[(size_t)tok * 512 + ch0] = o;
      }
    }
  }
}

// ---------------- MFMA attention: 1 wave per (window,head) -----------------
// St = K*Q^T (swapped)  ->  softmax per q-column  ->  P^T hi/lo via LDS
// out^T = Vt*Pt ; stores token-major fp16 (hi only) for the proj GEMM.
__global__ __launch_bounds__(128) void k_attn(
    const ushort_t* __restrict__ qph, const ushort_t* __restrict__ qpl,
    const ushort_t* __restrict__ kph, const ushort_t* __restrict__ kpl,
    const ushort_t* __restrict__ vt,
    const float* __restrict__ rpb, const float* __restrict__ lsc,
    ushort_t* __restrict__ oh) {
  __shared__ unsigned pw[2][2][64 * 36];   // [wave][P hi/lo][q row * 36 words]
  const int tid = threadIdx.x;
  const int wid = tid >> 6, lane = tid & 63;
  const int pair = blockIdx.x * 2 + wid;   // window*16 + head
  const int h = pair & 15;
  const int l15 = lane & 15, lq = lane >> 4;
  const size_t base = (size_t)pair * 2048;

  // ---- QK^T frags (A=K rows kv, B=Q cols q), 3 phases fp16x2 ----
  half8 Kh[4], Kl[4], Qh[4], Ql[4];
#pragma unroll
  for (int t4 = 0; t4 < 4; ++t4) {
    int off = (t4 * 16 + l15) * 32 + lq * 8;
    Kh[t4] = *(const half8*)(kph + base + off);
    Kl[t4] = *(const half8*)(kpl + base + off);
    Qh[t4] = *(const half8*)(qph + base + off);
    Ql[t4] = *(const half8*)(qpl + base + off);
  }
  f32x4 st[4][4];                          // [kvt][qt]
#pragma unroll
  for (int a = 0; a < 4; ++a)
#pragma unroll
    for (int b = 0; b < 4; ++b)
#pragma unroll
      for (int r = 0; r < 4; ++r) st[a][b][r] = 0.f;
#pragma unroll
  for (int kvt = 0; kvt < 4; ++kvt)
#pragma unroll
    for (int qt = 0; qt < 4; ++qt) {
      st[kvt][qt] = __builtin_amdgcn_mfma_f32_16x16x32_f16(Kh[kvt], Qh[qt], st[kvt][qt], 0, 0, 0);
      st[kvt][qt] = __builtin_amdgcn_mfma_f32_16x16x32_f16(Kh[kvt], Ql[qt], st[kvt][qt], 0, 0, 0);
      st[kvt][qt] = __builtin_amdgcn_mfma_f32_16x16x32_f16(Kl[kvt], Qh[qt], st[kvt][qt], 0, 0, 0);
    }

  // ---- logits + softmax (per q column; lanes {l15, +16, +32, +48} share q)
  const float ls = lsc[h];
  const float* rb = rpb + ((size_t)h << 12);
  float mx[4], sm[4], inv[4];
#pragma unroll
  for (int qt = 0; qt < 4; ++qt) {
    int qg = qt * 16 + l15;
    mx[qt] = -1e30f;
#pragma unroll
    for (int kvt = 0; kvt < 4; ++kvt) {
      f32x4 r4 = *(const f32x4*)(rb + qg * 64 + kvt * 16 + lq * 4);
#pragma unroll
      for (int r = 0; r < 4; ++r) {
        float z = st[kvt][qt][r] * ls + r4[r];
        st[kvt][qt][r] = z;
        mx[qt] = fmaxf(mx[qt], z);
      }
    }
    mx[qt] = fmaxf(mx[qt], __shfl_xor(mx[qt], 16));
    mx[qt] = fmaxf(mx[qt], __shfl_xor(mx[qt], 32));
    sm[qt] = 0.f;
#pragma unroll
    for (int kvt = 0; kvt < 4; ++kvt)
#pragma unroll
      for (int r = 0; r < 4; ++r) {
        float e = __expf(st[kvt][qt][r] - mx[qt]);
        st[kvt][qt][r] = e;
        sm[qt] += e;
      }
    sm[qt] += __shfl_xor(sm[qt], 16);
    sm[qt] += __shfl_xor(sm[qt], 32);
    inv[qt] = 1.f / sm[qt];
  }

  // ---- P^T hi/lo -> per-wave LDS (row stride 36 words = 144B, b128-aligned)
#pragma unroll
  for (int qt = 0; qt < 4; ++qt) {
    int qg = qt * 16 + l15;
#pragma unroll
    for (int kvt = 0; kvt < 4; ++kvt)
#pragma unroll
      for (int p2 = 0; p2 < 2; ++p2) {
        float pa = st[kvt][qt][2 * p2] * inv[qt];
        float pc = st[kvt][qt][2 * p2 + 1] * inv[qt];
        half_t ha = (half_t)pa, hc = (half_t)pc;
        unsigned wh = h_bits(ha) | ((unsigned)h_bits(hc) << 16);
        unsigned wl = h_bits((half_t)(pa - (float)ha)) |
                      ((unsigned)h_bits((half_t)(pc - (float)hc)) << 16);
        int kv = kvt * 16 + lq * 4 + 2 * p2;
        pw[wid][0][qg * 36 + (kv >> 1)] = wh;
        pw[wid][1][qg * 36 + (kv >> 1)] = wl;
      }
  }

  // ---- out^T = Vt * Pt  (V hi only; P hi+lo => 2 phases) ----
  half8 Vf[2][2];                          // [dt][ks]
#pragma unroll
  for (int dt = 0; dt < 2; ++dt)
#pragma unroll
    for (int ks = 0; ks < 2; ++ks)
      Vf[dt][ks] = *(const half8*)(vt + base + (dt * 16 + l15) * 64 + ks * 32 + lq * 8);
  f32x4 ot[2][4];                          // [dt][qt]
#pragma unroll
  for (int a = 0; a < 2; ++a)
#pragma unroll
    for (int b = 0; b < 4; ++b)
#pragma unroll
      for (int r = 0; r < 4; ++r) ot[a][b][r] = 0.f;
  const char* pb0 = (const char*)&pw[wid][0][0];
  const char* pb1 = (const char*)&pw[wid][1][0];
#pragma unroll
  for (int qt = 0; qt < 4; ++qt)
#pragma unroll
    for (int ks = 0; ks < 2; ++ks) {
      int off = (qt * 16 + l15) * 144 + ks * 64 + lq * 16;
      half8 Pf = *(const half8*)(pb0 + off);
      half8 Pl = *(const half8*)(pb1 + off);
#pragma unroll
      for (int dt = 0; dt < 2; ++dt) {
        ot[dt][qt] = __builtin_amdgcn_mfma_f32_16x16x32_f16(Vf[dt][ks], Pf, ot[dt][qt], 0, 0, 0);
        ot[dt][qt] = __builtin_amdgcn_mfma_f32_16x16x32_f16(Vf[dt][ks], Pl, ot[dt][qt], 0, 0, 0);
      }
    }

  // ---- store token-major fp16 (hi only): C col=token, row=d --------------
  int win = pair >> 4;
#pragma unroll
  for (int dt = 0; dt < 2; ++dt)
#pragma unroll
    for (int qt = 0; qt < 4; ++qt) {
      int t = win * 64 + qt * 16 + l15;
      int d0 = dt * 16 + lq * 4;
      ushort_t hb[4];
#pragma unroll
      for (int r = 0; r < 4; ++r) hb[r] = h_bits((half_t)ot[dt][qt][r]);
      uint2 hw = make_uint2(hb[0] | ((unsigned)hb[1] << 16), hb[2] | ((unsigned)hb[3] << 16));
      *(uint2*)&oh[(size_t)t * 512 + h * 32 + d0] = hw;
    }
}

// ---------------------------------------------------------------------------
extern "C" void kernel_launch(void* const* d_in, const int* in_sizes, int n_in,
                              void* d_out, int out_size, void* d_ws, size_t ws_size,
                              hipStream_t stream) {
  const float* x      = (const float*)d_in[0];
  const float* qkvw   = (const float*)d_in[1];
  const float* qb     = (const float*)d_in[2];
  const float* vb     = (const float*)d_in[3];
  const float* lsc    = (const float*)d_in[4];
  const float* w1     = (const float*)d_in[5];
  const float* b1     = (const float*)d_in[6];
  const float* w2     = (const float*)d_in[7];
  const float* pwt    = (const float*)d_in[8];
  const float* pb     = (const float*)d_in[9];
  const float* coords = (const float*)d_in[10];
  const int*   ridx   = (const int*)d_in[11];
  float* out = (float*)d_out;
  char* ws = (char*)d_ws;

  size_t off = 0;
  auto alloc = [&](size_t bytes) {
    size_t r = off;
    off = (off + bytes + 255) & ~(size_t)255;
    return r;
  };
  size_t oWQH = alloc((size_t)1536 * 512 * 2);
  size_t oWQL = alloc((size_t)1536 * 512 * 2);
  size_t oWPH = alloc((size_t)512 * 512 * 2);
  size_t oWPL = alloc((size_t)512 * 512 * 2);
  size_t oRPB = alloc((size_t)16 * 4096 * 4);
  size_t oTBL = alloc((size_t)225 * 16 * 4);
  size_t fixed = off;

  // slice so scratch fits: per slice need x hi/lo (2*Ms*1024B) + 5 fp16 planes
  int S = 1;
  while (S <= 32) {
    size_t Ms = (size_t)MROWS / S;
    size_t need = fixed + Ms * 1024 * 2 + Ms * 1024 * 5 + 4096;
    if (need <= ws_size) break;
    S <<= 1;
  }
  if (S > 64) S = 64;
  size_t Ms = (size_t)MROWS / S;

  size_t oXH = alloc(Ms * 1024);
  size_t oXL = alloc(Ms * 1024);
  size_t oQH = alloc(Ms * 1024);
  size_t oQL = alloc(Ms * 1024);
  size_t oKH = alloc(Ms * 1024);
  size_t oKL = alloc(Ms * 1024);
  size_t oVT = alloc(Ms * 1024);

  ushort_t* wqh = (ushort_t*)(ws + oWQH);
  ushort_t* wql = (ushort_t*)(ws + oWQL);
  ushort_t* wph = (ushort_t*)(ws + oWPH);
  ushort_t* wpl = (ushort_t*)(ws + oWPL);
  float* rpb = (float*)(ws + oRPB);
  float* tbl = (float*)(ws + oTBL);
  ushort_t* xh = (ushort_t*)(ws + oXH);
  ushort_t* xl = (ushort_t*)(ws + oXL);
  ushort_t* qh = (ushort_t*)(ws + oQH);
  ushort_t* ql = (ushort_t*)(ws + oQL);
  ushort_t* kh = (ushort_t*)(ws + oKH);
  ushort_t* kl = (ushort_t*)(ws + oKL);
  ushort_t* vt = (ushort_t*)(ws + oVT);

  k_split<<<768, 256, 0, stream>>>(qkvw, wqh, wql, 1536 * 512 / 4);
  k_split<<<256, 256, 0, stream>>>(pwt, wph, wpl, 512 * 512 / 4);
  k_cpb1<<<225, 256, 0, stream>>>(coords, w1, b1, w2, tbl);
  k_cpb2<<<256, 256, 0, stream>>>(tbl, ridx, rpb);

  int n4x = (int)(Ms * 512 / 4);
  int gsplit = (n4x + 255) / 256;
  if (gsplit > 2048) gsplit = 2048;
  int ntn = (int)(Ms / 128);
  int g0 = 12 * ntn;
  int g1 = 4 * ntn;
  int ga = (int)((Ms / 64) * 16 / 2);

  for (int s = 0; s < S; ++s) {
    const float* xs = x + (size_t)s * Ms * 512;
    k_split<<<gsplit, 256, 0, stream>>>(xs, xh, xl, n4x);
    k_gemm<0><<<g0, 256, 0, stream>>>(wqh, wql, xh, xl, 12, qb, vb,
                                      qh, ql, kh, kl, vt, nullptr, nullptr);
    // attention output (fp16 hi) goes back into xh; xl unused afterwards
    k_attn<<<ga, 128, 0, stream>>>(qh, ql, kh, kl, vt, rpb, lsc, xh);
    k_gemm<1><<<g1, 256, 0, stream>>>(wph, wpl, xh, xl, 4, nullptr, nullptr,
                                      nullptr, nullptr, nullptr, nullptr, nullptr,
                                      pb, out + (size_t)s * Ms * 512);
  }
  (void)in_sizes; (void)n_in; (void)out_size; (void)ws_size;
}

// Round 3
// 1015.196 us; speedup vs baseline: 1.3141x; 1.3141x over previous
//
#include <hip/hip_runtime.h>
#include <hip/hip_bf16.h>
#include <stdint.h>
#include <stddef.h>

// ---------------------------------------------------------------------------
// Swin-V2 window attention, MI355X.  fp16-hi/lo ("fp16x2") everywhere.
//   qkv GEMM (W-major, 3-phase)  ->  MFMA attention (fp16, P hi/lo via LDS)
//   -> proj GEMM (2-phase).
// GEMM0 epilogue emits q,k row-major and V TRANSPOSED, all in fp16 hi/lo,
// exactly matching the attention kernel's 16x16x32 fragment layouts.
// R3 fix: K-loop unroll capped at 2 (R2's full unroll = I-cache thrash,
// 900us/dispatch with both pipes <15% busy); no runtime-indexed ptr arrays.
// ---------------------------------------------------------------------------

typedef unsigned short ushort_t;
typedef _Float16 half_t;
typedef __attribute__((ext_vector_type(8))) _Float16 half8;   // 4 VGPR
typedef __attribute__((ext_vector_type(4))) float f32x4;

#define MROWS 65536   // 1024 windows * 64 tokens

__device__ __forceinline__ ushort_t h_bits(half_t h) {
  union { half_t h; ushort_t u; } c; c.h = h; return c.u;
}

// ---------------- split fp32 -> fp16 hi + fp16 lo --------------------------
__global__ __launch_bounds__(256) void k_split(const float* __restrict__ src,
                                               ushort_t* __restrict__ hi,
                                               ushort_t* __restrict__ lo, int n4) {
  int stride = gridDim.x * blockDim.x;
  for (int i = blockIdx.x * blockDim.x + threadIdx.x; i < n4; i += stride) {
    f32x4 x = reinterpret_cast<const f32x4*>(src)[i];
    ushort_t h4[4], l4[4];
#pragma unroll
    for (int j = 0; j < 4; ++j) {
      half_t hh = (half_t)x[j];
      h4[j] = h_bits(hh);
      l4[j] = h_bits((half_t)(x[j] - (float)hh));
    }
    uint2 hv = make_uint2(h4[0] | ((unsigned)h4[1] << 16), h4[2] | ((unsigned)h4[3] << 16));
    uint2 lv = make_uint2(l4[0] | ((unsigned)l4[1] << 16), l4[2] | ((unsigned)l4[3] << 16));
    reinterpret_cast<uint2*>(hi)[i] = hv;
    reinterpret_cast<uint2*>(lo)[i] = lv;
  }
}

// ---------------- CPB MLP: 225 positions -> 16*sigmoid table ---------------
__global__ __launch_bounds__(256) void k_cpb1(const float* __restrict__ coords,
                                              const float* __restrict__ w1,
                                              const float* __restrict__ b1,
                                              const float* __restrict__ w2,
                                              float* __restrict__ tbl) {
  __shared__ float hid[512];
  int p = blockIdx.x;
  float c0 = coords[2 * p], c1 = coords[2 * p + 1];
  int t = threadIdx.x;
  for (int j = t; j < 512; j += 256) {
    float v = c0 * w1[2 * j] + c1 * w1[2 * j + 1] + b1[j];
    hid[j] = v > 0.f ? v : 0.f;
  }
  __syncthreads();
  int wid = t >> 6, lane = t & 63;
#pragma unroll
  for (int hh = 0; hh < 4; ++hh) {
    int head = wid * 4 + hh;
    float s = 0.f;
    for (int j = lane; j < 512; j += 64) s += hid[j] * w2[head * 512 + j];
#pragma unroll
    for (int off = 32; off > 0; off >>= 1) s += __shfl_xor(s, off);
    if (lane == 0) tbl[p * 16 + head] = 16.f / (1.f + __expf(-s));
  }
}

__global__ __launch_bounds__(256) void k_cpb2(const float* __restrict__ tbl,
                                              const int* __restrict__ ridx,
                                              float* __restrict__ rpb) {
  int idx = blockIdx.x * 256 + threadIdx.x;   // 65536 = 16 heads * 4096
  int h = idx >> 12, nm = idx & 4095;
  rpb[idx] = tbl[ridx[nm] * 16 + h];
}

// ---------------- GEMM: C[ch, tok] = W[ch,K] * X[tok,K]^T  (fp16x2) --------
__device__ __forceinline__ void gload16(const void* g, void* l) {
  __builtin_amdgcn_global_load_lds(
      (const __attribute__((address_space(1))) unsigned int*)g,
      (__attribute__((address_space(3))) unsigned int*)l, 16, 0, 0);
}

// EPI 0: qkv epilogue -> q,k [pair][n][d] fp16 hi/lo ; v transposed hi only
// EPI 1: proj epilogue -> fp32 out[tok][512] (f32x4 stores)
template <int EPI>
__global__ __launch_bounds__(256) void k_gemm(
    const ushort_t* __restrict__ Ah, const ushort_t* __restrict__ Al,
    const ushort_t* __restrict__ Bh, const ushort_t* __restrict__ Bl,
    int ntm,
    const float* __restrict__ qb, const float* __restrict__ vb,
    ushort_t* __restrict__ oqh, ushort_t* __restrict__ oql,
    ushort_t* __restrict__ okh, ushort_t* __restrict__ okl,
    ushort_t* __restrict__ ovt,
    const float* __restrict__ pb, float* __restrict__ outp) {
  constexpr int NPH = (EPI == 0) ? 3 : 2;
  constexpr int NT = NPH * 16;
  __shared__ ushort_t lA[2][128 * 32];
  __shared__ ushort_t lB[2][128 * 32];

  int nwg = gridDim.x, bid = blockIdx.x;
  int idx = ((nwg & 7) == 0) ? ((bid & 7) * (nwg >> 3) + (bid >> 3)) : bid;
  int tm = idx % ntm;          // weight tile (channels)
  int tn = idx / ntm;          // token tile
  int tid = threadIdx.x;
  int wid = tid >> 6, lane = tid & 63;
  int wr = wid >> 1, wc = wid & 1;
  int lr = lane & 15, lq = lane >> 4;

  // staging: per-lane 32-bit plane offsets; plane base selected as uniform SGPR
  int rowA = tid >> 2;                          // 0..63
  int sw8 = ((tid & 3) ^ (rowA & 3)) * 8;       // source-side XOR swizzle
  int offA = (tm * 128 + rowA) * 512 + sw8;
  int offB = (tn * 128 + rowA) * 512 + sw8;

  f32x4 acc[4][4];
#pragma unroll
  for (int i = 0; i < 4; ++i)
#pragma unroll
    for (int j = 0; j < 4; ++j)
#pragma unroll
      for (int r = 0; r < 4; ++r) acc[i][j][r] = 0.f;

  auto stage = [&](int t, int bs) {
    int kk = (t & 15) * 32;
    const ushort_t* A;
    const ushort_t* B;
    if constexpr (EPI == 0) {          // phases: AhBh, AhBl, AlBh
      A = (t >= 32) ? Al : Ah;
      B = (t >= 16 && t < 32) ? Bl : Bh;
    } else {                           // phases: AhBh, AlBh
      A = (t >= 16) ? Al : Ah;
      B = Bh;
    }
    ushort_t* la = &lA[bs][wid * 512];
    ushort_t* lb = &lB[bs][wid * 512];
    gload16(A + offA + kk, la);
    gload16(A + offA + 32768 + kk, la + 2048);   // rows 64..127 (+64*512)
    gload16(B + offB + kk, lb);
    gload16(B + offB + 32768 + kk, lb + 2048);
  };

  stage(0, 0);
#pragma unroll 2
  for (int t = 0; t < NT; ++t) {
    __syncthreads();
    if (t + 1 < NT) stage(t + 1, (t + 1) & 1);
    int bs = t & 1;
    int c16 = (lq ^ (lr & 3)) * 8;     // inverse swizzle on the read side
    half8 af[4], bf[4];
#pragma unroll
    for (int i = 0; i < 4; ++i)
      af[i] = *(const half8*)&lA[bs][(wr * 64 + i * 16 + lr) * 32 + c16];
#pragma unroll
    for (int j = 0; j < 4; ++j)
      bf[j] = *(const half8*)&lB[bs][(wc * 64 + j * 16 + lr) * 32 + c16];
#pragma unroll
    for (int i = 0; i < 4; ++i)
#pragma unroll
      for (int j = 0; j < 4; ++j)
        acc[i][j] = __builtin_amdgcn_mfma_f32_16x16x32_f16(af[i], bf[j], acc[i][j], 0, 0, 0);
  }

  // C layout (verified): col = lane&15, row = (lane>>4)*4 + reg
  // W-major: row = out-channel, col = token.
#pragma unroll
  for (int i = 0; i < 4; ++i) {
    int ch0 = tm * 128 + wr * 64 + i * 16 + lq * 4;
#pragma unroll
    for (int j = 0; j < 4; ++j) {
      int tok = tn * 128 + wc * 64 + j * 16 + lr;
      if constexpr (EPI == 0) {
        int sec = tm >> 2;                 // block-uniform: 0=q,1=k,2=v
        int h = (ch0 >> 5) & 15, d0 = ch0 & 31;
        int win = tok >> 6, n = tok & 63;
        size_t pr = (size_t)win * 16 + h;
        f32x4 b4;
        if (sec == 0)      b4 = *(const f32x4*)&qb[ch0];
        else if (sec == 2) b4 = *(const f32x4*)&vb[ch0 - 1024];
        else { b4[0] = 0.f; b4[1] = 0.f; b4[2] = 0.f; b4[3] = 0.f; }
        if (sec == 2) {
#pragma unroll
          for (int r = 0; r < 4; ++r) {
            float v = acc[i][j][r] + b4[r];
            ovt[(pr * 32 + d0 + r) * 64 + n] = h_bits((half_t)v);
          }
        } else {
          ushort_t hb[4], lb4[4];
#pragma unroll
          for (int r = 0; r < 4; ++r) {
            float v = acc[i][j][r] + b4[r];
            half_t hh = (half_t)v;
            hb[r] = h_bits(hh);
            lb4[r] = h_bits((half_t)(v - (float)hh));
          }
          uint2 hw = make_uint2(hb[0] | ((unsigned)hb[1] << 16), hb[2] | ((unsigned)hb[3] << 16));
          uint2 lw = make_uint2(lb4[0] | ((unsigned)lb4[1] << 16), lb4[2] | ((unsigned)lb4[3] << 16));
          size_t o = (pr * 64 + n) * 32 + d0;
          if (sec == 0) { *(uint2*)&oqh[o] = hw; *(uint2*)&oql[o] = lw; }
          else          { *(uint2*)&okh[o] = hw; *(uint2*)&okl[o] = lw; }
        }
      } else {
        f32x4 b4 = *(const f32x4*)&pb[ch0];
        f32x4 o;
#pragma unroll
        for (int r = 0; r < 4; ++r) o[r] = acc[i][j][r] + b4[r];
        *(f32x4*)&outp[(size_t)tok * 512 + ch0] = o;
      }
    }
  }
}

// ---------------- MFMA attention: 1 wave per (window,head) -----------------
// St = K*Q^T (swapped)  ->  softmax per q-column  ->  P^T hi/lo via LDS
// out^T = Vt*Pt ; stores token-major fp16 (hi only) for the proj GEMM.
__global__ __launch_bounds__(128) void k_attn(
    const ushort_t* __restrict__ qph, const ushort_t* __restrict__ qpl,
    const ushort_t* __restrict__ kph, const ushort_t* __restrict__ kpl,
    const ushort_t* __restrict__ vt,
    const float* __restrict__ rpb, const float* __restrict__ lsc,
    ushort_t* __restrict__ oh) {
  __shared__ unsigned pw[2][2][64 * 36];   // [wave][P hi/lo][q row * 36 words]
  const int tid = threadIdx.x;
  const int wid = tid >> 6, lane = tid & 63;
  const int pair = blockIdx.x * 2 + wid;   // window*16 + head
  const int h = pair & 15;
  const int l15 = lane & 15, lq = lane >> 4;
  const size_t base = (size_t)pair * 2048;

  // ---- QK^T frags (A=K rows kv, B=Q cols q), 3 phases fp16x2 ----
  half8 Kh[4], Kl[4], Qh[4], Ql[4];
#pragma unroll
  for (int t4 = 0; t4 < 4; ++t4) {
    int off = (t4 * 16 + l15) * 32 + lq * 8;
    Kh[t4] = *(const half8*)(kph + base + off);
    Kl[t4] = *(const half8*)(kpl + base + off);
    Qh[t4] = *(const half8*)(qph + base + off);
    Ql[t4] = *(const half8*)(qpl + base + off);
  }
  f32x4 st[4][4];                          // [kvt][qt]
#pragma unroll
  for (int a = 0; a < 4; ++a)
#pragma unroll
    for (int b = 0; b < 4; ++b)
#pragma unroll
      for (int r = 0; r < 4; ++r) st[a][b][r] = 0.f;
#pragma unroll
  for (int kvt = 0; kvt < 4; ++kvt)
#pragma unroll
    for (int qt = 0; qt < 4; ++qt) {
      st[kvt][qt] = __builtin_amdgcn_mfma_f32_16x16x32_f16(Kh[kvt], Qh[qt], st[kvt][qt], 0, 0, 0);
      st[kvt][qt] = __builtin_amdgcn_mfma_f32_16x16x32_f16(Kh[kvt], Ql[qt], st[kvt][qt], 0, 0, 0);
      st[kvt][qt] = __builtin_amdgcn_mfma_f32_16x16x32_f16(Kl[kvt], Qh[qt], st[kvt][qt], 0, 0, 0);
    }

  // ---- logits + softmax (per q column; lanes {l15, +16, +32, +48} share q)
  const float ls = lsc[h];
  const float* rb = rpb + ((size_t)h << 12);
  float mx[4], sm[4], inv[4];
#pragma unroll
  for (int qt = 0; qt < 4; ++qt) {
    int qg = qt * 16 + l15;
    mx[qt] = -1e30f;
#pragma unroll
    for (int kvt = 0; kvt < 4; ++kvt) {
      f32x4 r4 = *(const f32x4*)(rb + qg * 64 + kvt * 16 + lq * 4);
#pragma unroll
      for (int r = 0; r < 4; ++r) {
        float z = st[kvt][qt][r] * ls + r4[r];
        st[kvt][qt][r] = z;
        mx[qt] = fmaxf(mx[qt], z);
      }
    }
    mx[qt] = fmaxf(mx[qt], __shfl_xor(mx[qt], 16));
    mx[qt] = fmaxf(mx[qt], __shfl_xor(mx[qt], 32));
    sm[qt] = 0.f;
#pragma unroll
    for (int kvt = 0; kvt < 4; ++kvt)
#pragma unroll
      for (int r = 0; r < 4; ++r) {
        float e = __expf(st[kvt][qt][r] - mx[qt]);
        st[kvt][qt][r] = e;
        sm[qt] += e;
      }
    sm[qt] += __shfl_xor(sm[qt], 16);
    sm[qt] += __shfl_xor(sm[qt], 32);
    inv[qt] = 1.f / sm[qt];
  }

  // ---- P^T hi/lo -> per-wave LDS (row stride 36 words = 144B, b128-aligned)
#pragma unroll
  for (int qt = 0; qt < 4; ++qt) {
    int qg = qt * 16 + l15;
#pragma unroll
    for (int kvt = 0; kvt < 4; ++kvt)
#pragma unroll
      for (int p2 = 0; p2 < 2; ++p2) {
        float pa = st[kvt][qt][2 * p2] * inv[qt];
        float pc = st[kvt][qt][2 * p2 + 1] * inv[qt];
        half_t ha = (half_t)pa, hc = (half_t)pc;
        unsigned wh = h_bits(ha) | ((unsigned)h_bits(hc) << 16);
        unsigned wl = h_bits((half_t)(pa - (float)ha)) |
                      ((unsigned)h_bits((half_t)(pc - (float)hc)) << 16);
        int kv = kvt * 16 + lq * 4 + 2 * p2;
        pw[wid][0][qg * 36 + (kv >> 1)] = wh;
        pw[wid][1][qg * 36 + (kv >> 1)] = wl;
      }
  }

  // ---- out^T = Vt * Pt  (V hi only; P hi+lo => 2 phases) ----
  half8 Vf[2][2];                          // [dt][ks]
#pragma unroll
  for (int dt = 0; dt < 2; ++dt)
#pragma unroll
    for (int ks = 0; ks < 2; ++ks)
      Vf[dt][ks] = *(const half8*)(vt + base + (dt * 16 + l15) * 64 + ks * 32 + lq * 8);
  f32x4 ot[2][4];                          // [dt][qt]
#pragma unroll
  for (int a = 0; a < 2; ++a)
#pragma unroll
    for (int b = 0; b < 4; ++b)
#pragma unroll
      for (int r = 0; r < 4; ++r) ot[a][b][r] = 0.f;
  const char* pb0 = (const char*)&pw[wid][0][0];
  const char* pb1 = (const char*)&pw[wid][1][0];
#pragma unroll
  for (int qt = 0; qt < 4; ++qt)
#pragma unroll
    for (int ks = 0; ks < 2; ++ks) {
      int off = (qt * 16 + l15) * 144 + ks * 64 + lq * 16;
      half8 Pf = *(const half8*)(pb0 + off);
      half8 Pl = *(const half8*)(pb1 + off);
#pragma unroll
      for (int dt = 0; dt < 2; ++dt) {
        ot[dt][qt] = __builtin_amdgcn_mfma_f32_16x16x32_f16(Vf[dt][ks], Pf, ot[dt][qt], 0, 0, 0);
        ot[dt][qt] = __builtin_amdgcn_mfma_f32_16x16x32_f16(Vf[dt][ks], Pl, ot[dt][qt], 0, 0, 0);
      }
    }

  // ---- store token-major fp16 (hi only): C col=token, row=d --------------
  int win = pair >> 4;
#pragma unroll
  for (int dt = 0; dt < 2; ++dt)
#pragma unroll
    for (int qt = 0; qt < 4; ++qt) {
      int t = win * 64 + qt * 16 + l15;
      int d0 = dt * 16 + lq * 4;
      ushort_t hb[4];
#pragma unroll
      for (int r = 0; r < 4; ++r) hb[r] = h_bits((half_t)ot[dt][qt][r]);
      uint2 hw = make_uint2(hb[0] | ((unsigned)hb[1] << 16), hb[2] | ((unsigned)hb[3] << 16));
      *(uint2*)&oh[(size_t)t * 512 + h * 32 + d0] = hw;
    }
}

// ---------------------------------------------------------------------------
extern "C" void kernel_launch(void* const* d_in, const int* in_sizes, int n_in,
                              void* d_out, int out_size, void* d_ws, size_t ws_size,
                              hipStream_t stream) {
  const float* x      = (const float*)d_in[0];
  const float* qkvw   = (const float*)d_in[1];
  const float* qb     = (const float*)d_in[2];
  const float* vb     = (const float*)d_in[3];
  const float* lsc    = (const float*)d_in[4];
  const float* w1     = (const float*)d_in[5];
  const float* b1     = (const float*)d_in[6];
  const float* w2     = (const float*)d_in[7];
  const float* pwt    = (const float*)d_in[8];
  const float* pb     = (const float*)d_in[9];
  const float* coords = (const float*)d_in[10];
  const int*   ridx   = (const int*)d_in[11];
  float* out = (float*)d_out;
  char* ws = (char*)d_ws;

  size_t off = 0;
  auto alloc = [&](size_t bytes) {
    size_t r = off;
    off = (off + bytes + 255) & ~(size_t)255;
    return r;
  };
  size_t oWQH = alloc((size_t)1536 * 512 * 2);
  size_t oWQL = alloc((size_t)1536 * 512 * 2);
  size_t oWPH = alloc((size_t)512 * 512 * 2);
  size_t oWPL = alloc((size_t)512 * 512 * 2);
  size_t oRPB = alloc((size_t)16 * 4096 * 4);
  size_t oTBL = alloc((size_t)225 * 16 * 4);
  size_t fixed = off;

  // slice so scratch fits: per slice need x hi/lo (2*Ms*1024B) + 5 fp16 planes
  int S = 1;
  while (S <= 32) {
    size_t Ms = (size_t)MROWS / S;
    size_t need = fixed + Ms * 1024 * 2 + Ms * 1024 * 5 + 4096;
    if (need <= ws_size) break;
    S <<= 1;
  }
  if (S > 64) S = 64;
  size_t Ms = (size_t)MROWS / S;

  size_t oXH = alloc(Ms * 1024);
  size_t oXL = alloc(Ms * 1024);
  size_t oQH = alloc(Ms * 1024);
  size_t oQL = alloc(Ms * 1024);
  size_t oKH = alloc(Ms * 1024);
  size_t oKL = alloc(Ms * 1024);
  size_t oVT = alloc(Ms * 1024);

  ushort_t* wqh = (ushort_t*)(ws + oWQH);
  ushort_t* wql = (ushort_t*)(ws + oWQL);
  ushort_t* wph = (ushort_t*)(ws + oWPH);
  ushort_t* wpl = (ushort_t*)(ws + oWPL);
  float* rpb = (float*)(ws + oRPB);
  float* tbl = (float*)(ws + oTBL);
  ushort_t* xh = (ushort_t*)(ws + oXH);
  ushort_t* xl = (ushort_t*)(ws + oXL);
  ushort_t* qh = (ushort_t*)(ws + oQH);
  ushort_t* ql = (ushort_t*)(ws + oQL);
  ushort_t* kh = (ushort_t*)(ws + oKH);
  ushort_t* kl = (ushort_t*)(ws + oKL);
  ushort_t* vt = (ushort_t*)(ws + oVT);

  k_split<<<768, 256, 0, stream>>>(qkvw, wqh, wql, 1536 * 512 / 4);
  k_split<<<256, 256, 0, stream>>>(pwt, wph, wpl, 512 * 512 / 4);
  k_cpb1<<<225, 256, 0, stream>>>(coords, w1, b1, w2, tbl);
  k_cpb2<<<256, 256, 0, stream>>>(tbl, ridx, rpb);

  int n4x = (int)(Ms * 512 / 4);
  int gsplit = (n4x + 255) / 256;
  if (gsplit > 2048) gsplit = 2048;
  int ntn = (int)(Ms / 128);
  int g0 = 12 * ntn;
  int g1 = 4 * ntn;
  int ga = (int)((Ms / 64) * 16 / 2);

  for (int s = 0; s < S; ++s) {
    const float* xs = x + (size_t)s * Ms * 512;
    k_split<<<gsplit, 256, 0, stream>>>(xs, xh, xl, n4x);
    k_gemm<0><<<g0, 256, 0, stream>>>(wqh, wql, xh, xl, 12, qb, vb,
                                      qh, ql, kh, kl, vt, nullptr, nullptr);
    // attention output (fp16 hi) goes back into xh; xl unused afterwards
    k_attn<<<ga, 128, 0, stream>>>(qh, ql, kh, kl, vt, rpb, lsc, xh);
    k_gemm<1><<<g1, 256, 0, stream>>>(wph, wpl, xh, xl, 4, nullptr, nullptr,
                                      nullptr, nullptr, nullptr, nullptr, nullptr,
                                      pb, out + (size_t)s * Ms * 512);
  }
  (void)in_sizes; (void)n_in; (void)out_size; (void)ws_size;
}

// Round 5
// 843.914 us; speedup vs baseline: 1.5809x; 1.2030x over previous
//
#include <hip/hip_runtime.h>
#include <hip/hip_bf16.h>
#include <stdint.h>
#include <stddef.h>

// ---------------------------------------------------------------------------
// Swin-V2 window attention, MI355X.  fp16-hi/lo ("fp16x2") everywhere.
// R4: fused-phase GEMMs. All hi/lo planes for a K-step co-resident in LDS:
//   k_qkv : x read as fp32, split to fp16 hi/lo IN-KERNEL (reg-stage + swizzled
//           ds_write), weights via global_load_lds; 48 MFMA per barrier-pair.
//   k_proj: Wh+Wl co-resident, attn-out staged once; 32 MFMA per barrier-pair.
// Eliminates the x-split kernel and 2 of 3 B-plane passes.
// (R5 = R4 resubmitted verbatim: R4 bench never ran — GPU acquisition timeout.)
// ---------------------------------------------------------------------------

typedef unsigned short ushort_t;
typedef _Float16 half_t;
typedef __attribute__((ext_vector_type(8))) _Float16 half8;   // 4 VGPR
typedef __attribute__((ext_vector_type(4))) float f32x4;

#define MROWS 65536   // 1024 windows * 64 tokens

__device__ __forceinline__ ushort_t h_bits(half_t h) {
  union { half_t h; ushort_t u; } c; c.h = h; return c.u;
}

__device__ __forceinline__ void gload16(const void* g, void* l) {
  __builtin_amdgcn_global_load_lds(
      (const __attribute__((address_space(1))) unsigned int*)g,
      (__attribute__((address_space(3))) unsigned int*)l, 16, 0, 0);
}

// ---------------- split fp32 -> fp16 hi + fp16 lo (weights only now) -------
__global__ __launch_bounds__(256) void k_split(const float* __restrict__ src,
                                               ushort_t* __restrict__ hi,
                                               ushort_t* __restrict__ lo, int n4) {
  int stride = gridDim.x * blockDim.x;
  for (int i = blockIdx.x * blockDim.x + threadIdx.x; i < n4; i += stride) {
    f32x4 x = reinterpret_cast<const f32x4*>(src)[i];
    ushort_t h4[4], l4[4];
#pragma unroll
    for (int j = 0; j < 4; ++j) {
      half_t hh = (half_t)x[j];
      h4[j] = h_bits(hh);
      l4[j] = h_bits((half_t)(x[j] - (float)hh));
    }
    reinterpret_cast<uint2*>(hi)[i] =
        make_uint2(h4[0] | ((unsigned)h4[1] << 16), h4[2] | ((unsigned)h4[3] << 16));
    reinterpret_cast<uint2*>(lo)[i] =
        make_uint2(l4[0] | ((unsigned)l4[1] << 16), l4[2] | ((unsigned)l4[3] << 16));
  }
}

// ---------------- CPB MLP: 225 positions -> 16*sigmoid table ---------------
__global__ __launch_bounds__(256) void k_cpb1(const float* __restrict__ coords,
                                              const float* __restrict__ w1,
                                              const float* __restrict__ b1,
                                              const float* __restrict__ w2,
                                              float* __restrict__ tbl) {
  __shared__ float hid[512];
  int p = blockIdx.x;
  float c0 = coords[2 * p], c1 = coords[2 * p + 1];
  int t = threadIdx.x;
  for (int j = t; j < 512; j += 256) {
    float v = c0 * w1[2 * j] + c1 * w1[2 * j + 1] + b1[j];
    hid[j] = v > 0.f ? v : 0.f;
  }
  __syncthreads();
  int wid = t >> 6, lane = t & 63;
#pragma unroll
  for (int hh = 0; hh < 4; ++hh) {
    int head = wid * 4 + hh;
    float s = 0.f;
    for (int j = lane; j < 512; j += 64) s += hid[j] * w2[head * 512 + j];
#pragma unroll
    for (int off = 32; off > 0; off >>= 1) s += __shfl_xor(s, off);
    if (lane == 0) tbl[p * 16 + head] = 16.f / (1.f + __expf(-s));
  }
}

__global__ __launch_bounds__(256) void k_cpb2(const float* __restrict__ tbl,
                                              const int* __restrict__ ridx,
                                              float* __restrict__ rpb) {
  int idx = blockIdx.x * 256 + threadIdx.x;   // 65536 = 16 heads * 4096
  int h = idx >> 12, nm = idx & 4095;
  rpb[idx] = tbl[ridx[nm] * 16 + h];
}

// ---------------- QKV GEMM: C[ch,tok] = W[ch,K] * X[tok,K]^T ---------------
// A = W fp16 hi/lo via global_load_lds; B = x fp32 reg-staged -> hi/lo LDS.
// Per K-step (32): 48 MFMAs (AhBh + AhBl + AlBh). 16 K-steps.
__global__ __launch_bounds__(256, 2) void k_qkv(
    const ushort_t* __restrict__ Wh, const ushort_t* __restrict__ Wl,
    const float* __restrict__ X,
    const float* __restrict__ qb, const float* __restrict__ vb,
    ushort_t* __restrict__ oqh, ushort_t* __restrict__ oql,
    ushort_t* __restrict__ okh, ushort_t* __restrict__ okl,
    ushort_t* __restrict__ ovt) {
  __shared__ ushort_t lAh[2][4096];
  __shared__ ushort_t lAl[2][4096];
  __shared__ ushort_t lBh[2][4096];
  __shared__ ushort_t lBl[2][4096];

  int nwg = gridDim.x, bid = blockIdx.x;
  int idx = ((nwg & 7) == 0) ? ((bid & 7) * (nwg >> 3) + (bid >> 3)) : bid;
  int tm = idx % 12, tn = idx / 12;    // 12 consecutive idx share tn (x L2 reuse)
  int tid = threadIdx.x;
  int wid = tid >> 6, lane = tid & 63;
  int wr = wid >> 1, wc = wid & 1;
  int lr = lane & 15, lq = lane >> 4;

  // A staging (gload_lds, linear dest + source-side XOR swizzle), 2 sweeps/plane
  int rA = tid >> 2, qA = tid & 3;              // rows rA, rA+64
  size_t gA = (size_t)(tm * 128 + rA) * 512 + ((qA ^ (rA & 3)) << 3);
  int dA = wid * 512;                           // ushort units; sweep adds 2048

  // B reg-stage: 4 sweeps; thread owns (row = s*32 + rB, cols qB*4..+3)
  int rB = tid >> 3, qB = tid & 7;
  const float* gB = X + (size_t)(tn * 128 + rB) * 512 + qB * 4;  // + s*16384 + kk
  int dB = rB * 32 + (((qB >> 1) ^ (rB & 3)) << 3) + ((qB & 1) << 2);  // + s*1024

  f32x4 acc[4][4];
#pragma unroll
  for (int i = 0; i < 4; ++i)
#pragma unroll
    for (int j = 0; j < 4; ++j)
#pragma unroll
      for (int r = 0; r < 4; ++r) acc[i][j][r] = 0.f;

  auto stageA = [&](int kk, int bs) {
    gload16(Wh + gA + kk, &lAh[bs][dA]);
    gload16(Wh + gA + 32768 + kk, &lAh[bs][2048 + dA]);
    gload16(Wl + gA + kk, &lAl[bs][dA]);
    gload16(Wl + gA + 32768 + kk, &lAl[bs][2048 + dA]);
  };
  auto loadB = [&](int kk, f32x4* xr) {
#pragma unroll
    for (int s = 0; s < 4; ++s) xr[s] = *(const f32x4*)(gB + s * 16384 + kk);
  };
  auto writeB = [&](const f32x4* xr, int bs) {
#pragma unroll
    for (int s = 0; s < 4; ++s) {
      ushort_t h4[4], l4[4];
#pragma unroll
      for (int e = 0; e < 4; ++e) {
        half_t hh = (half_t)xr[s][e];
        h4[e] = h_bits(hh);
        l4[e] = h_bits((half_t)(xr[s][e] - (float)hh));
      }
      *(uint2*)&lBh[bs][dB + s * 1024] =
          make_uint2(h4[0] | ((unsigned)h4[1] << 16), h4[2] | ((unsigned)h4[3] << 16));
      *(uint2*)&lBl[bs][dB + s * 1024] =
          make_uint2(l4[0] | ((unsigned)l4[1] << 16), l4[2] | ((unsigned)l4[3] << 16));
    }
  };

  f32x4 xr[4];
  stageA(0, 0);
  loadB(0, xr);
  writeB(xr, 0);
  const int c16 = (lq ^ (lr & 3)) << 3;   // read-side inverse swizzle
#pragma unroll 2
  for (int t = 0; t < 16; ++t) {
    __syncthreads();
    int bs = t & 1;
    if (t < 15) {
      stageA((t + 1) * 32, bs ^ 1);
      loadB((t + 1) * 32, xr);
    }
    half8 ah[4], al[4], bh[4], bl[4];
#pragma unroll
    for (int i = 0; i < 4; ++i) {
      int ro = (wr * 64 + i * 16 + lr) * 32 + c16;
      ah[i] = *(const half8*)&lAh[bs][ro];
      al[i] = *(const half8*)&lAl[bs][ro];
    }
#pragma unroll
    for (int j = 0; j < 4; ++j) {
      int ro = (wc * 64 + j * 16 + lr) * 32 + c16;
      bh[j] = *(const half8*)&lBh[bs][ro];
      bl[j] = *(const half8*)&lBl[bs][ro];
    }
#pragma unroll
    for (int i = 0; i < 4; ++i)
#pragma unroll
      for (int j = 0; j < 4; ++j) {
        acc[i][j] = __builtin_amdgcn_mfma_f32_16x16x32_f16(ah[i], bh[j], acc[i][j], 0, 0, 0);
        acc[i][j] = __builtin_amdgcn_mfma_f32_16x16x32_f16(ah[i], bl[j], acc[i][j], 0, 0, 0);
        acc[i][j] = __builtin_amdgcn_mfma_f32_16x16x32_f16(al[i], bh[j], acc[i][j], 0, 0, 0);
      }
    if (t < 15) writeB(xr, bs ^ 1);
  }

  // C layout: col = lane&15 (token), row = (lane>>4)*4 + reg (channel)
#pragma unroll
  for (int i = 0; i < 4; ++i) {
    int ch0 = tm * 128 + wr * 64 + i * 16 + lq * 4;
#pragma unroll
    for (int j = 0; j < 4; ++j) {
      int tok = tn * 128 + wc * 64 + j * 16 + lr;
      int sec = tm >> 2;                 // block-uniform: 0=q,1=k,2=v
      int h = (ch0 >> 5) & 15, d0 = ch0 & 31;
      int win = tok >> 6, n = tok & 63;
      size_t pr = (size_t)win * 16 + h;
      f32x4 b4;
      if (sec == 0)      b4 = *(const f32x4*)&qb[ch0];
      else if (sec == 2) b4 = *(const f32x4*)&vb[ch0 - 1024];
      else { b4[0] = 0.f; b4[1] = 0.f; b4[2] = 0.f; b4[3] = 0.f; }
      if (sec == 2) {
#pragma unroll
        for (int r = 0; r < 4; ++r) {
          float v = acc[i][j][r] + b4[r];
          ovt[(pr * 32 + d0 + r) * 64 + n] = h_bits((half_t)v);
        }
      } else {
        ushort_t hb[4], lb4[4];
#pragma unroll
        for (int r = 0; r < 4; ++r) {
          float v = acc[i][j][r] + b4[r];
          half_t hh = (half_t)v;
          hb[r] = h_bits(hh);
          lb4[r] = h_bits((half_t)(v - (float)hh));
        }
        uint2 hw = make_uint2(hb[0] | ((unsigned)hb[1] << 16), hb[2] | ((unsigned)hb[3] << 16));
        uint2 lw = make_uint2(lb4[0] | ((unsigned)lb4[1] << 16), lb4[2] | ((unsigned)lb4[3] << 16));
        size_t o = (pr * 64 + n) * 32 + d0;
        if (sec == 0) { *(uint2*)&oqh[o] = hw; *(uint2*)&oql[o] = lw; }
        else          { *(uint2*)&okh[o] = hw; *(uint2*)&okl[o] = lw; }
      }
    }
  }
}

// ---------------- proj GEMM: C[ch,tok] = W[ch,K] * AO[tok,K]^T -------------
// A = Wp hi/lo co-resident; B = attn-out fp16 (hi only). 32 MFMA / barrier.
__global__ __launch_bounds__(256, 2) void k_proj(
    const ushort_t* __restrict__ Wh, const ushort_t* __restrict__ Wl,
    const ushort_t* __restrict__ Bp,
    const float* __restrict__ pb, float* __restrict__ outp) {
  __shared__ ushort_t lAh[2][4096];
  __shared__ ushort_t lAl[2][4096];
  __shared__ ushort_t lBh[2][4096];

  int nwg = gridDim.x, bid = blockIdx.x;
  int idx = ((nwg & 7) == 0) ? ((bid & 7) * (nwg >> 3) + (bid >> 3)) : bid;
  int tm = idx % 4, tn = idx / 4;
  int tid = threadIdx.x;
  int wid = tid >> 6, lane = tid & 63;
  int wr = wid >> 1, wc = wid & 1;
  int lr = lane & 15, lq = lane >> 4;

  int rA = tid >> 2, qA = tid & 3;
  int sw = (qA ^ (rA & 3)) << 3;
  size_t gA = (size_t)(tm * 128 + rA) * 512 + sw;
  size_t gB = (size_t)(tn * 128 + rA) * 512 + sw;
  int dA = wid * 512;

  f32x4 acc[4][4];
#pragma unroll
  for (int i = 0; i < 4; ++i)
#pragma unroll
    for (int j = 0; j < 4; ++j)
#pragma unroll
      for (int r = 0; r < 4; ++r) acc[i][j][r] = 0.f;

  auto stage = [&](int kk, int bs) {
    gload16(Wh + gA + kk, &lAh[bs][dA]);
    gload16(Wh + gA + 32768 + kk, &lAh[bs][2048 + dA]);
    gload16(Wl + gA + kk, &lAl[bs][dA]);
    gload16(Wl + gA + 32768 + kk, &lAl[bs][2048 + dA]);
    gload16(Bp + gB + kk, &lBh[bs][dA]);
    gload16(Bp + gB + 32768 + kk, &lBh[bs][2048 + dA]);
  };

  stage(0, 0);
  const int c16 = (lq ^ (lr & 3)) << 3;
#pragma unroll 2
  for (int t = 0; t < 16; ++t) {
    __syncthreads();
    int bs = t & 1;
    if (t < 15) stage((t + 1) * 32, bs ^ 1);
    half8 ah[4], al[4], bh[4];
#pragma unroll
    for (int i = 0; i < 4; ++i) {
      int ro = (wr * 64 + i * 16 + lr) * 32 + c16;
      ah[i] = *(const half8*)&lAh[bs][ro];
      al[i] = *(const half8*)&lAl[bs][ro];
    }
#pragma unroll
    for (int j = 0; j < 4; ++j)
      bh[j] = *(const half8*)&lBh[bs][(wc * 64 + j * 16 + lr) * 32 + c16];
#pragma unroll
    for (int i = 0; i < 4; ++i)
#pragma unroll
      for (int j = 0; j < 4; ++j) {
        acc[i][j] = __builtin_amdgcn_mfma_f32_16x16x32_f16(ah[i], bh[j], acc[i][j], 0, 0, 0);
        acc[i][j] = __builtin_amdgcn_mfma_f32_16x16x32_f16(al[i], bh[j], acc[i][j], 0, 0, 0);
      }
  }

#pragma unroll
  for (int i = 0; i < 4; ++i) {
    int ch0 = tm * 128 + wr * 64 + i * 16 + lq * 4;
    f32x4 b4 = *(const f32x4*)&pb[ch0];
#pragma unroll
    for (int j = 0; j < 4; ++j) {
      int tok = tn * 128 + wc * 64 + j * 16 + lr;
      f32x4 o;
#pragma unroll
      for (int r = 0; r < 4; ++r) o[r] = acc[i][j][r] + b4[r];
      *(f32x4*)&outp[(size_t)tok * 512 + ch0] = o;
    }
  }
}

// ---------------- MFMA attention: 1 wave per (window,head) -----------------
__global__ __launch_bounds__(128) void k_attn(
    const ushort_t* __restrict__ qph, const ushort_t* __restrict__ qpl,
    const ushort_t* __restrict__ kph, const ushort_t* __restrict__ kpl,
    const ushort_t* __restrict__ vt,
    const float* __restrict__ rpb, const float* __restrict__ lsc,
    ushort_t* __restrict__ oh) {
  __shared__ unsigned pw[2][2][64 * 36];   // [wave][P hi/lo][q row * 36 words]
  const int tid = threadIdx.x;
  const int wid = tid >> 6, lane = tid & 63;
  const int pair = blockIdx.x * 2 + wid;   // window*16 + head
  const int h = pair & 15;
  const int l15 = lane & 15, lq = lane >> 4;
  const size_t base = (size_t)pair * 2048;

  half8 Kh[4], Kl[4], Qh[4], Ql[4];
#pragma unroll
  for (int t4 = 0; t4 < 4; ++t4) {
    int off = (t4 * 16 + l15) * 32 + lq * 8;
    Kh[t4] = *(const half8*)(kph + base + off);
    Kl[t4] = *(const half8*)(kpl + base + off);
    Qh[t4] = *(const half8*)(qph + base + off);
    Ql[t4] = *(const half8*)(qpl + base + off);
  }
  f32x4 st[4][4];                          // [kvt][qt]
#pragma unroll
  for (int a = 0; a < 4; ++a)
#pragma unroll
    for (int b = 0; b < 4; ++b)
#pragma unroll
      for (int r = 0; r < 4; ++r) st[a][b][r] = 0.f;
#pragma unroll
  for (int kvt = 0; kvt < 4; ++kvt)
#pragma unroll
    for (int qt = 0; qt < 4; ++qt) {
      st[kvt][qt] = __builtin_amdgcn_mfma_f32_16x16x32_f16(Kh[kvt], Qh[qt], st[kvt][qt], 0, 0, 0);
      st[kvt][qt] = __builtin_amdgcn_mfma_f32_16x16x32_f16(Kh[kvt], Ql[qt], st[kvt][qt], 0, 0, 0);
      st[kvt][qt] = __builtin_amdgcn_mfma_f32_16x16x32_f16(Kl[kvt], Qh[qt], st[kvt][qt], 0, 0, 0);
    }

  const float ls = lsc[h];
  const float* rb = rpb + ((size_t)h << 12);
  float mx[4], sm[4], inv[4];
#pragma unroll
  for (int qt = 0; qt < 4; ++qt) {
    int qg = qt * 16 + l15;
    mx[qt] = -1e30f;
#pragma unroll
    for (int kvt = 0; kvt < 4; ++kvt) {
      f32x4 r4 = *(const f32x4*)(rb + qg * 64 + kvt * 16 + lq * 4);
#pragma unroll
      for (int r = 0; r < 4; ++r) {
        float z = st[kvt][qt][r] * ls + r4[r];
        st[kvt][qt][r] = z;
        mx[qt] = fmaxf(mx[qt], z);
      }
    }
    mx[qt] = fmaxf(mx[qt], __shfl_xor(mx[qt], 16));
    mx[qt] = fmaxf(mx[qt], __shfl_xor(mx[qt], 32));
    sm[qt] = 0.f;
#pragma unroll
    for (int kvt = 0; kvt < 4; ++kvt)
#pragma unroll
      for (int r = 0; r < 4; ++r) {
        float e = __expf(st[kvt][qt][r] - mx[qt]);
        st[kvt][qt][r] = e;
        sm[qt] += e;
      }
    sm[qt] += __shfl_xor(sm[qt], 16);
    sm[qt] += __shfl_xor(sm[qt], 32);
    inv[qt] = 1.f / sm[qt];
  }

#pragma unroll
  for (int qt = 0; qt < 4; ++qt) {
    int qg = qt * 16 + l15;
#pragma unroll
    for (int kvt = 0; kvt < 4; ++kvt)
#pragma unroll
      for (int p2 = 0; p2 < 2; ++p2) {
        float pa = st[kvt][qt][2 * p2] * inv[qt];
        float pc = st[kvt][qt][2 * p2 + 1] * inv[qt];
        half_t ha = (half_t)pa, hc = (half_t)pc;
        unsigned wh = h_bits(ha) | ((unsigned)h_bits(hc) << 16);
        unsigned wl = h_bits((half_t)(pa - (float)ha)) |
                      ((unsigned)h_bits((half_t)(pc - (float)hc)) << 16);
        int kv = kvt * 16 + lq * 4 + 2 * p2;
        pw[wid][0][qg * 36 + (kv >> 1)] = wh;
        pw[wid][1][qg * 36 + (kv >> 1)] = wl;
      }
  }

  half8 Vf[2][2];                          // [dt][ks]
#pragma unroll
  for (int dt = 0; dt < 2; ++dt)
#pragma unroll
    for (int ks = 0; ks < 2; ++ks)
      Vf[dt][ks] = *(const half8*)(vt + base + (dt * 16 + l15) * 64 + ks * 32 + lq * 8);
  f32x4 ot[2][4];                          // [dt][qt]
#pragma unroll
  for (int a = 0; a < 2; ++a)
#pragma unroll
    for (int b = 0; b < 4; ++b)
#pragma unroll
      for (int r = 0; r < 4; ++r) ot[a][b][r] = 0.f;
  const char* pb0 = (const char*)&pw[wid][0][0];
  const char* pb1 = (const char*)&pw[wid][1][0];
#pragma unroll
  for (int qt = 0; qt < 4; ++qt)
#pragma unroll
    for (int ks = 0; ks < 2; ++ks) {
      int off = (qt * 16 + l15) * 144 + ks * 64 + lq * 16;
      half8 Pf = *(const half8*)(pb0 + off);
      half8 Pl = *(const half8*)(pb1 + off);
#pragma unroll
      for (int dt = 0; dt < 2; ++dt) {
        ot[dt][qt] = __builtin_amdgcn_mfma_f32_16x16x32_f16(Vf[dt][ks], Pf, ot[dt][qt], 0, 0, 0);
        ot[dt][qt] = __builtin_amdgcn_mfma_f32_16x16x32_f16(Vf[dt][ks], Pl, ot[dt][qt], 0, 0, 0);
      }
    }

  int win = pair >> 4;
#pragma unroll
  for (int dt = 0; dt < 2; ++dt)
#pragma unroll
    for (int qt = 0; qt < 4; ++qt) {
      int t = win * 64 + qt * 16 + l15;
      int d0 = dt * 16 + lq * 4;
      ushort_t hb[4];
#pragma unroll
      for (int r = 0; r < 4; ++r) hb[r] = h_bits((half_t)ot[dt][qt][r]);
      *(uint2*)&oh[(size_t)t * 512 + h * 32 + d0] =
          make_uint2(hb[0] | ((unsigned)hb[1] << 16), hb[2] | ((unsigned)hb[3] << 16));
    }
}

// ---------------------------------------------------------------------------
extern "C" void kernel_launch(void* const* d_in, const int* in_sizes, int n_in,
                              void* d_out, int out_size, void* d_ws, size_t ws_size,
                              hipStream_t stream) {
  const float* x      = (const float*)d_in[0];
  const float* qkvw   = (const float*)d_in[1];
  const float* qb     = (const float*)d_in[2];
  const float* vb     = (const float*)d_in[3];
  const float* lsc    = (const float*)d_in[4];
  const float* w1     = (const float*)d_in[5];
  const float* b1     = (const float*)d_in[6];
  const float* w2     = (const float*)d_in[7];
  const float* pwt    = (const float*)d_in[8];
  const float* pb     = (const float*)d_in[9];
  const float* coords = (const float*)d_in[10];
  const int*   ridx   = (const int*)d_in[11];
  float* out = (float*)d_out;
  char* ws = (char*)d_ws;

  size_t off = 0;
  auto alloc = [&](size_t bytes) {
    size_t r = off;
    off = (off + bytes + 255) & ~(size_t)255;
    return r;
  };
  size_t oWQH = alloc((size_t)1536 * 512 * 2);
  size_t oWQL = alloc((size_t)1536 * 512 * 2);
  size_t oWPH = alloc((size_t)512 * 512 * 2);
  size_t oWPL = alloc((size_t)512 * 512 * 2);
  size_t oRPB = alloc((size_t)16 * 4096 * 4);
  size_t oTBL = alloc((size_t)225 * 16 * 4);
  size_t fixed = off;

  // per-slice planes: qh,ql,kh,kl,vt,ao = 6 * Ms*1024 bytes
  int S = 1;
  while (S <= 32) {
    size_t Ms = (size_t)MROWS / S;
    size_t need = fixed + Ms * 1024 * 6 + 4096;
    if (need <= ws_size) break;
    S <<= 1;
  }
  if (S > 64) S = 64;
  size_t Ms = (size_t)MROWS / S;

  size_t oQH = alloc(Ms * 1024);
  size_t oQL = alloc(Ms * 1024);
  size_t oKH = alloc(Ms * 1024);
  size_t oKL = alloc(Ms * 1024);
  size_t oVT = alloc(Ms * 1024);
  size_t oAO = alloc(Ms * 1024);

  ushort_t* wqh = (ushort_t*)(ws + oWQH);
  ushort_t* wql = (ushort_t*)(ws + oWQL);
  ushort_t* wph = (ushort_t*)(ws + oWPH);
  ushort_t* wpl = (ushort_t*)(ws + oWPL);
  float* rpb = (float*)(ws + oRPB);
  float* tbl = (float*)(ws + oTBL);
  ushort_t* qh = (ushort_t*)(ws + oQH);
  ushort_t* ql = (ushort_t*)(ws + oQL);
  ushort_t* kh = (ushort_t*)(ws + oKH);
  ushort_t* kl = (ushort_t*)(ws + oKL);
  ushort_t* vt = (ushort_t*)(ws + oVT);
  ushort_t* ao = (ushort_t*)(ws + oAO);

  k_split<<<768, 256, 0, stream>>>(qkvw, wqh, wql, 1536 * 512 / 4);
  k_split<<<256, 256, 0, stream>>>(pwt, wph, wpl, 512 * 512 / 4);
  k_cpb1<<<225, 256, 0, stream>>>(coords, w1, b1, w2, tbl);
  k_cpb2<<<256, 256, 0, stream>>>(tbl, ridx, rpb);

  int ntn = (int)(Ms / 128);
  int g0 = 12 * ntn;
  int g1 = 4 * ntn;
  int ga = (int)((Ms / 64) * 16 / 2);

  for (int s = 0; s < S; ++s) {
    const float* xs = x + (size_t)s * Ms * 512;
    k_qkv<<<g0, 256, 0, stream>>>(wqh, wql, xs, qb, vb, qh, ql, kh, kl, vt);
    k_attn<<<ga, 128, 0, stream>>>(qh, ql, kh, kl, vt, rpb, lsc, ao);
    k_proj<<<g1, 256, 0, stream>>>(wph, wpl, ao, pb, out + (size_t)s * Ms * 512);
  }
  (void)in_sizes; (void)n_in; (void)out_size; (void)ws_size;
}